// Round 2
// baseline (133.269 us; speedup 1.0000x reference)
//
#include <hip/hip_runtime.h>
#include <hip/hip_bf16.h>

// DIAGNOSTIC ROUND: pure fp32 VALU AWQ GEMM. No bf16, no MFMA, no LDS.
// Shares dequant/index logic (AWQ shift map, group indexing, split-K+reduce)
// with the round-1 MFMA kernel to isolate which half contains the bug.
//
// x[16,4096] fp32  *  dequant(qweight)[4096,11008]  + bias -> out[16,11008]

#define K_DIM 4096
#define N_DIM 11008
#define M_DIM 16
#define NPACK 1376   // N/8

// thread -> (word w: 8 output cols, mg: 4 m-rows, ks: K-split chunk)
// grid (11, 4, split), block 128. nstep = K/split (multiple of 128).
__global__ __launch_bounds__(128) void gemm_valu(
    const int* __restrict__ qw, const int* __restrict__ qz,
    const float* __restrict__ scales, const float* __restrict__ x,
    float* __restrict__ part, int nstep) {
  int w = blockIdx.x * 128 + threadIdx.x;
  if (w >= NPACK) return;          // tail lanes idle; no barriers in kernel
  int mg = blockIdx.y;             // m rows mg*4 .. mg*4+3
  int ks = blockIdx.z;
  int k0 = ks * nstep;

  float acc[4][8];
#pragma unroll
  for (int i = 0; i < 4; ++i)
#pragma unroll
    for (int j = 0; j < 8; ++j) acc[i][j] = 0.f;

  for (int g0 = 0; g0 < nstep; g0 += 128) {   // one scale-group of k
    int g = (k0 + g0) >> 7;
    int zw = qz[g * NPACK + w];
    float s[8], z[8];
#pragma unroll
    for (int j = 0; j < 8; ++j) {
      // AWQ reverse order {0,4,1,5,2,6,3,7}: col j <- nibble shift 4*ARO[j]
      int sh = ((j & 1) << 4) | ((j >> 1) << 2);
      s[j] = scales[g * N_DIM + w * 8 + j];
      z[j] = -s[j] * (float)((zw >> sh) & 15);
    }
    for (int kk = 0; kk < 128; ++kk) {
      int k = k0 + g0 + kk;
      int qword = qw[k * NPACK + w];
      float wv[8];
#pragma unroll
      for (int j = 0; j < 8; ++j) {
        int sh = ((j & 1) << 4) | ((j >> 1) << 2);
        wv[j] = fmaf((float)((qword >> sh) & 15), s[j], z[j]);
      }
#pragma unroll
      for (int i = 0; i < 4; ++i) {
        float xv = x[(mg * 4 + i) * K_DIM + k];   // wave-uniform, L1-hot
#pragma unroll
        for (int j = 0; j < 8; ++j)
          acc[i][j] = fmaf(xv, wv[j], acc[i][j]);
      }
    }
  }

  float* pb = part + (size_t)ks * (M_DIM * N_DIM);
#pragma unroll
  for (int i = 0; i < 4; ++i)
#pragma unroll
    for (int j = 0; j < 8; ++j)
      pb[(mg * 4 + i) * N_DIM + w * 8 + j] = acc[i][j];
}

__global__ __launch_bounds__(256) void reduce_bias(
    const float* __restrict__ part, const float* __restrict__ bias,
    float* __restrict__ out, int split) {
  int i = blockIdx.x * 256 + threadIdx.x;  // float4 index over M*N/4
  if (i >= (M_DIM * N_DIM) / 4) return;
  int n = (i << 2) % N_DIM;                // N_DIM % 4 == 0
  float4 a = *reinterpret_cast<const float4*>(bias + n);
  for (int s = 0; s < split; ++s) {
    float4 p = reinterpret_cast<const float4*>(part)[(size_t)s * (M_DIM * N_DIM / 4) + i];
    a.x += p.x; a.y += p.y; a.z += p.z; a.w += p.w;
  }
  reinterpret_cast<float4*>(out)[i] = a;
}

extern "C" void kernel_launch(void* const* d_in, const int* in_sizes, int n_in,
                              void* d_out, int out_size, void* d_ws, size_t ws_size,
                              hipStream_t stream) {
  const float* x      = (const float*)d_in[0];
  const int*   qwp    = (const int*)d_in[1];
  const int*   qzp    = (const int*)d_in[2];
  const float* scales = (const float*)d_in[3];
  const float* bias   = (const float*)d_in[4];
  float* out = (float*)d_out;

  const size_t PART_ELEMS = (size_t)M_DIM * N_DIM;  // 176128 floats per split

  int split = 32;
  while (split > 1 && (size_t)split * PART_ELEMS * 4 > ws_size) split >>= 1;
  float* part = (float*)d_ws;
  if ((size_t)split * PART_ELEMS * 4 > ws_size) {
    split = 1;          // ws too small even for one partial: write into out
    part = out;
  }
  int nstep = K_DIM / split;  // multiple of 128 for split in {1..32}

  gemm_valu<<<dim3(11, 4, split), 128, 0, stream>>>(qwp, qzp, scales, x, part, nstep);
  reduce_bias<<<(M_DIM * N_DIM / 4 + 255) / 256, 256, 0, stream>>>(part, bias, out, split);
}

// Round 3
// 96.332 us; speedup vs baseline: 1.3834x; 1.3834x over previous
//
#include <hip/hip_runtime.h>

// AWQ W4A16 GEMM via bf16 MFMA. x[16,4096] fp32 * dq(qweight)[4096,11008] + bias.
// Round-2-proven shell (split-K + reduce_bias + dequant formulas) with a
// freshly-derived MFMA core. No x-precast kernel: A-fragments built from fp32 x.

typedef __attribute__((ext_vector_type(8))) short bf16x8;
typedef __attribute__((ext_vector_type(4))) float f32x4;

#define K_DIM 4096
#define N_DIM 11008
#define M_DIM 16
#define NPACK 1376   // N/8 packed words per k-row
#define NCB   86     // 11008 / 128 columns per block

static __device__ __forceinline__ unsigned short f2bf(float f) {
  unsigned u = __builtin_bit_cast(unsigned, f);
  u += 0x7fffu + ((u >> 16) & 1u);   // RNE, finite values only
  return (unsigned short)(u >> 16);
}

// grid (NCB, split), block 256 (4 waves). Block: 128 cols (16 words), nstep*32 k.
// nstep is a multiple of 4 so each block spans whole 128-k scale groups.
__global__ __launch_bounds__(256) void gemm_awq(
    const int* __restrict__ qw, const int* __restrict__ qz,
    const float* __restrict__ scales, const float* __restrict__ x,
    float* __restrict__ part, int nstep) {
  // [word 0..15][k 0..31], pad to 36 ints: row base 144 B (16B-aligned),
  // read/write bank aliasing <= 2-way (free).
  __shared__ int qt[16][36];

  int cb = blockIdx.x;
  int ks = blockIdx.y;
  int n0 = cb * 128;           // first output col of this block
  int w0 = cb * 16;            // first packed word
  int k0 = ks * nstep * 32;    // first k

  int tid  = threadIdx.x;
  int lane = tid & 63;
  int wv   = tid >> 6;         // wave id: cols n0+32*wv .. +31
  int c15  = lane & 15;        // col within 16-tile; also A row m
  int kg   = lane >> 4;        // fragment k-group (8 k each)

  // AWQ nibble shift for col j = n%8, order {0,4,1,5,2,6,3,7} (round-2-proven)
  int j  = c15 & 7;
  int sh = ((j & 1) << 4) | ((j >> 1) << 2);

  // word-in-row this lane's fragment reads: (n-n0)/8
  int wloc = wv * 4 + 2 * 0 + (c15 >> 3);  // + 2*c added per col-tile below

  // staging: thread t -> k-row t>>3, word pair (t&7)*2 (int2, 64B/row/8 lanes)
  int srow = tid >> 3;         // 0..31
  int swd  = (tid & 7) * 2;    // 0,2,..,14
  const int* gq = qw + (size_t)(k0 + srow) * NPACK + w0 + swd;

  f32x4 acc[2] = {{0, 0, 0, 0}, {0, 0, 0, 0}};

  int ngroups = nstep >> 2;
  for (int g = 0; g < ngroups; ++g) {
    int gid = (k0 >> 7) + g;   // scale-group index (k0 is a multiple of 128)
    float s[2], z[2];
#pragma unroll
    for (int c = 0; c < 2; ++c) {
      int n = n0 + wv * 32 + c * 16 + c15;
      float sv = scales[gid * N_DIM + n];
      int zw   = qz[gid * NPACK + w0 + wloc + 2 * c];
      s[c] = sv;
      z[c] = -sv * (float)((zw >> sh) & 15);
    }

#pragma unroll
    for (int t4 = 0; t4 < 4; ++t4) {
      int kk = g * 4 + t4;     // k-step (32 k) within block

      // ---- stage 16 words x 32 k of qweight into LDS ----
      int2 q2 = *reinterpret_cast<const int2*>(gq + (size_t)kk * 32 * NPACK);
      __syncthreads();                       // prior reads done before overwrite
      qt[swd + 0][srow] = q2.x;
      qt[swd + 1][srow] = q2.y;
      __syncthreads();                       // writes visible

      // ---- A fragment: x[m=c15][k0+kk*32+kg*8 .. +7], fp32 -> bf16 ----
      const float* xp = x + c15 * K_DIM + k0 + kk * 32 + kg * 8;
      float4 x0 = *reinterpret_cast<const float4*>(xp);
      float4 x1 = *reinterpret_cast<const float4*>(xp + 4);
      union { bf16x8 v; unsigned short u[8]; } a;
      a.u[0] = f2bf(x0.x); a.u[1] = f2bf(x0.y);
      a.u[2] = f2bf(x0.z); a.u[3] = f2bf(x0.w);
      a.u[4] = f2bf(x1.x); a.u[5] = f2bf(x1.y);
      a.u[6] = f2bf(x1.z); a.u[7] = f2bf(x1.w);

      // ---- 2 col-tiles: dequant B fragment from LDS, MFMA ----
#pragma unroll
      for (int c = 0; c < 2; ++c) {
        const int* cp = &qt[wloc + 2 * c][kg * 8];
        int4 qa = *reinterpret_cast<const int4*>(cp);      // k = kg*8 .. +3
        int4 qb = *reinterpret_cast<const int4*>(cp + 4);  // k = kg*8+4 .. +7
        union { bf16x8 v; unsigned short u[8]; } b;
        float sv = s[c], zv = z[c];
        b.u[0] = f2bf(fmaf((float)((qa.x >> sh) & 15), sv, zv));
        b.u[1] = f2bf(fmaf((float)((qa.y >> sh) & 15), sv, zv));
        b.u[2] = f2bf(fmaf((float)((qa.z >> sh) & 15), sv, zv));
        b.u[3] = f2bf(fmaf((float)((qa.w >> sh) & 15), sv, zv));
        b.u[4] = f2bf(fmaf((float)((qb.x >> sh) & 15), sv, zv));
        b.u[5] = f2bf(fmaf((float)((qb.y >> sh) & 15), sv, zv));
        b.u[6] = f2bf(fmaf((float)((qb.z >> sh) & 15), sv, zv));
        b.u[7] = f2bf(fmaf((float)((qb.w >> sh) & 15), sv, zv));
        acc[c] = __builtin_amdgcn_mfma_f32_16x16x32_bf16(a.v, b.v, acc[c], 0, 0, 0);
      }
    }
  }

  // ---- epilogue: D col = lane&15, row = (lane>>4)*4 + r (m89-verified) ----
  float* pb = part + (size_t)ks * (M_DIM * N_DIM);
#pragma unroll
  for (int c = 0; c < 2; ++c) {
    int n = n0 + wv * 32 + c * 16 + c15;
#pragma unroll
    for (int r = 0; r < 4; ++r) {
      pb[(kg * 4 + r) * N_DIM + n] = acc[c][r];
    }
  }
}

// verbatim round-2-proven reduce
__global__ __launch_bounds__(256) void reduce_bias(
    const float* __restrict__ part, const float* __restrict__ bias,
    float* __restrict__ out, int split) {
  int i = blockIdx.x * 256 + threadIdx.x;  // float4 index over M*N/4
  if (i >= (M_DIM * N_DIM) / 4) return;
  int n = (i << 2) % N_DIM;                // N_DIM % 4 == 0
  float4 a = *reinterpret_cast<const float4*>(bias + n);
  for (int s = 0; s < split; ++s) {
    float4 p = reinterpret_cast<const float4*>(part)[(size_t)s * (M_DIM * N_DIM / 4) + i];
    a.x += p.x; a.y += p.y; a.z += p.z; a.w += p.w;
  }
  reinterpret_cast<float4*>(out)[i] = a;
}

extern "C" void kernel_launch(void* const* d_in, const int* in_sizes, int n_in,
                              void* d_out, int out_size, void* d_ws, size_t ws_size,
                              hipStream_t stream) {
  const float* x      = (const float*)d_in[0];
  const int*   qwp    = (const int*)d_in[1];
  const int*   qzp    = (const int*)d_in[2];
  const float* scales = (const float*)d_in[3];
  const float* bias   = (const float*)d_in[4];
  float* out = (float*)d_out;

  const size_t PART_ELEMS = (size_t)M_DIM * N_DIM;  // 176128 floats per slice

  int split = 16;
  while (split > 1 && (size_t)split * PART_ELEMS * 4 > ws_size) split >>= 1;
  float* part = (float*)d_ws;
  if ((size_t)split * PART_ELEMS * 4 > ws_size) {
    split = 1;        // ws too small even for one slice: partials into out,
    part = out;       // reduce_bias then adds bias in place (round-2-proven)
  }
  int nstep = 128 / split;  // k-steps of 32 per block; multiple of 4

  gemm_awq<<<dim3(NCB, split), 256, 0, stream>>>(qwp, qzp, scales, x, part, nstep);
  reduce_bias<<<(M_DIM * N_DIM / 4 + 255) / 256, 256, 0, stream>>>(part, bias, out, split);
}

// Round 4
// 95.236 us; speedup vs baseline: 1.3994x; 1.0115x over previous
//
#include <hip/hip_runtime.h>

// AWQ W4A16 GEMM, x[16,4096] fp32 * dq(qweight)[4096,11008] + bias.
// Round-4: exact-int MFMA (B = 128+q via 0x4300|nibble, per-group fold with
// ones-MFMA row sums) + double-buffered LDS with depth-1 prefetch, 1 barrier
// per k-step. Shell (split-K + reduce_bias + AWQ shift map) proven rounds 2-3.

typedef __attribute__((ext_vector_type(8))) short bf16x8;
typedef __attribute__((ext_vector_type(4))) float f32x4;

#define K_DIM 4096
#define N_DIM 11008
#define M_DIM 16
#define NPACK 1376   // N/8 packed words per k-row
#define NCB   86     // 11008 / 128 cols per block

static __device__ __forceinline__ unsigned short f2bf(float f) {
  unsigned u = __builtin_bit_cast(unsigned, f);
  u += 0x7fffu + ((u >> 16) & 1u);   // RNE, finite only
  return (unsigned short)(u >> 16);
}

// Fast path: split=16 -> 8 k-steps of 32 per block, fully unrolled.
__global__ __launch_bounds__(256) void gemm_awq_fast(
    const int* __restrict__ qw, const int* __restrict__ qz,
    const float* __restrict__ scales, const float* __restrict__ x,
    float* __restrict__ part) {
  constexpr int NSTEP = 8;
  // double-buffered transposed tile [buf][word][k], pad 36 (round-3-proven)
  __shared__ int qt[2][16][36];

  int cb = blockIdx.x, ks = blockIdx.y;
  int n0 = cb * 128, w0 = cb * 16, k0 = ks * (NSTEP * 32);

  int tid = threadIdx.x, lane = tid & 63, wv = tid >> 6;
  int c15 = lane & 15;         // col within 16-tile; also A row m
  int kg  = lane >> 4;         // fragment k-group
  int j   = c15 & 7;
  int sh  = ((j & 1) << 4) | ((j >> 1) << 2);  // AWQ {0,4,1,5,2,6,3,7} (proven)
  int wloc = wv * 4 + (c15 >> 3);              // word-in-tile, + 2*c per col-tile

  // staging: thread t -> k-row t>>3, words (t&7)*2 (int2)
  int srow = tid >> 3, swd = (tid & 7) * 2;
  const int* gq = qw + (size_t)(k0 + srow) * NPACK + w0 + swd;

  union { bf16x8 v; unsigned short u[8]; } ones;
#pragma unroll
  for (int i = 0; i < 8; ++i) ones.u[i] = 0x3F80;  // bf16 1.0

  const f32x4 vzero = {0.f, 0.f, 0.f, 0.f};
  f32x4 macc[2] = {vzero, vzero};   // final f32 result
  f32x4 pacc[2] = {vzero, vzero};   // per-group raw  sum x*(128+q)
  f32x4 xacc    = vzero;            // per-group row sums  X(m)
  float s[2], zn[2];

  // prologue: stage k-step 0 into buf 0
  {
    int2 q0 = *reinterpret_cast<const int2*>(gq);
    qt[0][swd + 0][srow] = q0.x;
    qt[0][swd + 1][srow] = q0.y;
  }
  __syncthreads();

#pragma unroll
  for (int kk = 0; kk < NSTEP; ++kk) {
    const int cur = kk & 1;

    // depth-1 prefetch: issue next tile's global load before compute
    int2 qn;
    if (kk + 1 < NSTEP)
      qn = *reinterpret_cast<const int2*>(gq + (size_t)(kk + 1) * 32 * NPACK);

    if ((kk & 3) == 0) {  // new 128-k scale group
      int gid = (k0 >> 7) + (kk >> 2);
#pragma unroll
      for (int c = 0; c < 2; ++c) {
        int n = n0 + wv * 32 + c * 16 + c15;
        s[c] = scales[gid * N_DIM + n];
        int zw = qz[gid * NPACK + w0 + wloc + 2 * c];
        zn[c] = -(float)(((zw >> sh) & 15) + 128);  // -(z+128)
      }
    }

    // A fragment: bf16(x[m=c15][k0 + kk*32 + kg*8 ..+7])
    const float* xp = x + c15 * K_DIM + k0 + kk * 32 + kg * 8;
    float4 x0 = *reinterpret_cast<const float4*>(xp);
    float4 x1 = *reinterpret_cast<const float4*>(xp + 4);
    union { bf16x8 v; unsigned short u[8]; } a;
    a.u[0] = f2bf(x0.x); a.u[1] = f2bf(x0.y);
    a.u[2] = f2bf(x0.z); a.u[3] = f2bf(x0.w);
    a.u[4] = f2bf(x1.x); a.u[5] = f2bf(x1.y);
    a.u[6] = f2bf(x1.z); a.u[7] = f2bf(x1.w);

    // B fragments: exact bf16(128 + nibble) = 0x4300 | nibble
#pragma unroll
    for (int c = 0; c < 2; ++c) {
      const int* cp = &qt[cur][wloc + 2 * c][kg * 8];
      int4 qa = *reinterpret_cast<const int4*>(cp);      // ds_read_b128
      int4 qb = *reinterpret_cast<const int4*>(cp + 4);  // ds_read_b128
      union { bf16x8 v; unsigned short u[8]; } b;
      b.u[0] = (unsigned short)(0x4300 | ((qa.x >> sh) & 15));
      b.u[1] = (unsigned short)(0x4300 | ((qa.y >> sh) & 15));
      b.u[2] = (unsigned short)(0x4300 | ((qa.z >> sh) & 15));
      b.u[3] = (unsigned short)(0x4300 | ((qa.w >> sh) & 15));
      b.u[4] = (unsigned short)(0x4300 | ((qb.x >> sh) & 15));
      b.u[5] = (unsigned short)(0x4300 | ((qb.y >> sh) & 15));
      b.u[6] = (unsigned short)(0x4300 | ((qb.z >> sh) & 15));
      b.u[7] = (unsigned short)(0x4300 | ((qb.w >> sh) & 15));
      pacc[c] = __builtin_amdgcn_mfma_f32_16x16x32_bf16(a.v, b.v, pacc[c], 0, 0, 0);
    }
    // row sums X(m) in matching D-layout
    xacc = __builtin_amdgcn_mfma_f32_16x16x32_bf16(a.v, ones.v, xacc, 0, 0, 0);

    if ((kk & 3) == 3) {  // group fold: out += s * (P' - (z+128)*X)
#pragma unroll
      for (int c = 0; c < 2; ++c)
#pragma unroll
        for (int r = 0; r < 4; ++r) {
          float t = fmaf(zn[c], xacc[r], pacc[c][r]);
          macc[c][r] = fmaf(s[c], t, macc[c][r]);
        }
      pacc[0] = vzero; pacc[1] = vzero; xacc = vzero;
    }

    // write prefetched tile into the other buffer (readers of it were
    // separated by the previous iteration's barrier)
    if (kk + 1 < NSTEP) {
      qt[cur ^ 1][swd + 0][srow] = qn.x;
      qt[cur ^ 1][swd + 1][srow] = qn.y;
    }
    __syncthreads();
  }

  // epilogue: D col = lane&15, row = (lane>>4)*4 + r (m89-verified)
  float* pb = part + (size_t)ks * (M_DIM * N_DIM);
#pragma unroll
  for (int c = 0; c < 2; ++c) {
    int n = n0 + wv * 32 + c * 16 + c15;
#pragma unroll
    for (int r = 0; r < 4; ++r)
      pb[(kg * 4 + r) * N_DIM + n] = macc[c][r];
  }
}

// Generic fallback (round-3-proven verbatim core), used only if ws is small.
__global__ __launch_bounds__(256) void gemm_awq_generic(
    const int* __restrict__ qw, const int* __restrict__ qz,
    const float* __restrict__ scales, const float* __restrict__ x,
    float* __restrict__ part, int nstep) {
  __shared__ int qt[16][36];
  int cb = blockIdx.x, ks = blockIdx.y;
  int n0 = cb * 128, w0 = cb * 16, k0 = ks * nstep * 32;
  int tid = threadIdx.x, lane = tid & 63, wv = tid >> 6;
  int c15 = lane & 15, kg = lane >> 4;
  int j = c15 & 7;
  int sh = ((j & 1) << 4) | ((j >> 1) << 2);
  int wloc = wv * 4 + (c15 >> 3);
  int srow = tid >> 3, swd = (tid & 7) * 2;
  const int* gq = qw + (size_t)(k0 + srow) * NPACK + w0 + swd;
  f32x4 acc[2] = {{0,0,0,0},{0,0,0,0}};
  int ngroups = nstep >> 2;
  for (int g = 0; g < ngroups; ++g) {
    int gid = (k0 >> 7) + g;
    float s[2], z[2];
#pragma unroll
    for (int c = 0; c < 2; ++c) {
      int n = n0 + wv * 32 + c * 16 + c15;
      float sv = scales[gid * N_DIM + n];
      int zw = qz[gid * NPACK + w0 + wloc + 2 * c];
      s[c] = sv; z[c] = -sv * (float)((zw >> sh) & 15);
    }
#pragma unroll
    for (int t4 = 0; t4 < 4; ++t4) {
      int kk = g * 4 + t4;
      int2 q2 = *reinterpret_cast<const int2*>(gq + (size_t)kk * 32 * NPACK);
      __syncthreads();
      qt[swd + 0][srow] = q2.x;
      qt[swd + 1][srow] = q2.y;
      __syncthreads();
      const float* xp = x + c15 * K_DIM + k0 + kk * 32 + kg * 8;
      float4 x0 = *reinterpret_cast<const float4*>(xp);
      float4 x1 = *reinterpret_cast<const float4*>(xp + 4);
      union { bf16x8 v; unsigned short u[8]; } a;
      a.u[0]=f2bf(x0.x); a.u[1]=f2bf(x0.y); a.u[2]=f2bf(x0.z); a.u[3]=f2bf(x0.w);
      a.u[4]=f2bf(x1.x); a.u[5]=f2bf(x1.y); a.u[6]=f2bf(x1.z); a.u[7]=f2bf(x1.w);
#pragma unroll
      for (int c = 0; c < 2; ++c) {
        const int* cp = &qt[wloc + 2 * c][kg * 8];
        int4 qa = *reinterpret_cast<const int4*>(cp);
        int4 qb = *reinterpret_cast<const int4*>(cp + 4);
        union { bf16x8 v; unsigned short u[8]; } b;
        float sv = s[c], zv = z[c];
        b.u[0] = f2bf(fmaf((float)((qa.x >> sh) & 15), sv, zv));
        b.u[1] = f2bf(fmaf((float)((qa.y >> sh) & 15), sv, zv));
        b.u[2] = f2bf(fmaf((float)((qa.z >> sh) & 15), sv, zv));
        b.u[3] = f2bf(fmaf((float)((qa.w >> sh) & 15), sv, zv));
        b.u[4] = f2bf(fmaf((float)((qb.x >> sh) & 15), sv, zv));
        b.u[5] = f2bf(fmaf((float)((qb.y >> sh) & 15), sv, zv));
        b.u[6] = f2bf(fmaf((float)((qb.z >> sh) & 15), sv, zv));
        b.u[7] = f2bf(fmaf((float)((qb.w >> sh) & 15), sv, zv));
        acc[c] = __builtin_amdgcn_mfma_f32_16x16x32_bf16(a.v, b.v, acc[c], 0, 0, 0);
      }
    }
  }
  float* pb = part + (size_t)ks * (M_DIM * N_DIM);
#pragma unroll
  for (int c = 0; c < 2; ++c) {
    int n = n0 + wv * 32 + c * 16 + c15;
#pragma unroll
    for (int r = 0; r < 4; ++r)
      pb[(kg * 4 + r) * N_DIM + n] = acc[c][r];
  }
}

// verbatim round-2-proven reduce
__global__ __launch_bounds__(256) void reduce_bias(
    const float* __restrict__ part, const float* __restrict__ bias,
    float* __restrict__ out, int split) {
  int i = blockIdx.x * 256 + threadIdx.x;
  if (i >= (M_DIM * N_DIM) / 4) return;
  int n = (i << 2) % N_DIM;
  float4 a = *reinterpret_cast<const float4*>(bias + n);
  for (int s = 0; s < split; ++s) {
    float4 p = reinterpret_cast<const float4*>(part)[(size_t)s * (M_DIM * N_DIM / 4) + i];
    a.x += p.x; a.y += p.y; a.z += p.z; a.w += p.w;
  }
  reinterpret_cast<float4*>(out)[i] = a;
}

extern "C" void kernel_launch(void* const* d_in, const int* in_sizes, int n_in,
                              void* d_out, int out_size, void* d_ws, size_t ws_size,
                              hipStream_t stream) {
  const float* x      = (const float*)d_in[0];
  const int*   qwp    = (const int*)d_in[1];
  const int*   qzp    = (const int*)d_in[2];
  const float* scales = (const float*)d_in[3];
  const float* bias   = (const float*)d_in[4];
  float* out = (float*)d_out;

  const size_t PART_ELEMS = (size_t)M_DIM * N_DIM;

  int split = 16;
  while (split > 1 && (size_t)split * PART_ELEMS * 4 > ws_size) split >>= 1;
  float* part = (float*)d_ws;
  if ((size_t)split * PART_ELEMS * 4 > ws_size) {
    split = 1;
    part = out;   // reduce_bias then adds bias in place (proven)
  }

  if (split == 16) {
    gemm_awq_fast<<<dim3(NCB, 16), 256, 0, stream>>>(qwp, qzp, scales, x, part);
  } else {
    int nstep = 128 / split;
    gemm_awq_generic<<<dim3(NCB, split), 256, 0, stream>>>(qwp, qzp, scales, x, part, nstep);
  }
  reduce_bias<<<(M_DIM * N_DIM / 4 + 255) / 256, 256, 0, stream>>>(part, bias, out, split);
}

// Round 5
// 93.243 us; speedup vs baseline: 1.4293x; 1.0214x over previous
//
#include <hip/hip_runtime.h>

// AWQ W4A16 GEMM: x[16,4096] fp32 * dq(qweight)[4096,11008] + bias.
// Round-5: 256-col blocks (128B-line-aligned qweight reads), prep'd bf16 x,
// hoisted A-fragments/scales, BK=64 double-buffered stages, exact-int MFMA
// (B = 128+q, per-group fold via ones-MFMA row sums). split-K=16 + reduce.

typedef __attribute__((ext_vector_type(8))) short bf16x8;
typedef __attribute__((ext_vector_type(4))) float f32x4;

#define K_DIM 4096
#define N_DIM 11008
#define M_DIM 16
#define NPACK 1376    // N/8 packed words per k-row
#define NCB256 43     // 11008 / 256 cols per block (fast path)
#define NCB128 86     // fallback path

static __device__ __forceinline__ unsigned short f2bf(float f) {
  unsigned u = __builtin_bit_cast(unsigned, f);
  u += 0x7fffu + ((u >> 16) & 1u);   // RNE, finite only
  return (unsigned short)(u >> 16);
}

__global__ __launch_bounds__(256) void prep_x(const float* __restrict__ x,
                                              unsigned short* __restrict__ xb) {
  int i = blockIdx.x * 256 + threadIdx.x;  // 16384 float4 = 65536 elems
  float4 v = reinterpret_cast<const float4*>(x)[i];
  ushort4 o;
  o.x = f2bf(v.x); o.y = f2bf(v.y); o.z = f2bf(v.z); o.w = f2bf(v.w);
  reinterpret_cast<ushort4*>(xb)[i] = o;
}

// grid (43, 16), block 512 (8 waves). Block: 256 cols (32 words), 256 k.
// 4 stages of BK=64, double-buffered, depth-1 reg prefetch, 1 barrier/stage.
__global__ __launch_bounds__(512) void gemm_awq_fast(
    const int* __restrict__ qw, const int* __restrict__ qz,
    const float* __restrict__ scales, const unsigned short* __restrict__ xb,
    float* __restrict__ part) {
  // [buf][word 0..31][k 0..63] pad 68: row base 272B (16B-aligned for b128);
  // fragment reads hit all 32 banks exactly once (verified); writes <=4-way.
  __shared__ int qt[2][32][68];

  int cb = blockIdx.x, ks = blockIdx.y;
  int n0 = cb * 256, w0 = cb * 32, k0 = ks * 256;

  int tid = threadIdx.x, lane = tid & 63, wv = tid >> 6;  // wv 0..7
  int c15 = lane & 15;          // col within 16-tile; also A row m
  int kg  = lane >> 4;          // fragment k-group (8 k)
  int j   = c15 & 7;
  int sh  = ((j & 1) << 4) | ((j >> 1) << 2);  // AWQ {0,4,1,5,2,6,3,7} (proven)
  int wloc = wv * 4 + (c15 >> 3);              // word-in-tile, +2c per col-tile

  // staging: thread t -> k-row t>>3 (0..63), words (t&7)*4 (int4 = 16B)
  // one wave = 8 k-rows x 128B contiguous (exactly one cache line each)
  int srow = tid >> 3, sw4 = (tid & 7) * 4;
  const int* gq = qw + (size_t)(k0 + srow) * NPACK + w0 + sw4;

  union { bf16x8 v; unsigned short u[8]; } ones;
#pragma unroll
  for (int i = 0; i < 8; ++i) ones.u[i] = 0x3F80;  // bf16 1.0

  // ---- prologue: stage 0, A fragments, scales/zeros (all hoisted) ----
  {
    int4 q0 = *reinterpret_cast<const int4*>(gq);
    qt[0][sw4 + 0][srow] = q0.x;
    qt[0][sw4 + 1][srow] = q0.y;
    qt[0][sw4 + 2][srow] = q0.z;
    qt[0][sw4 + 3][srow] = q0.w;
  }

  bf16x8 a[8];
#pragma unroll
  for (int kk = 0; kk < 8; ++kk)
    a[kk] = *reinterpret_cast<const bf16x8*>(xb + c15 * K_DIM + k0 + kk * 32 + kg * 8);

  float s[2][2], zn[2][2];
#pragma unroll
  for (int g = 0; g < 2; ++g) {
    int gid = ks * 2 + g;
#pragma unroll
    for (int c = 0; c < 2; ++c) {
      int n = n0 + wv * 32 + c * 16 + c15;
      s[g][c] = scales[gid * N_DIM + n];
      int zw = qz[gid * NPACK + w0 + wloc + 2 * c];
      zn[g][c] = -(float)(((zw >> sh) & 15) + 128);  // -(z+128)
    }
  }

  const f32x4 vzero = {0.f, 0.f, 0.f, 0.f};
  f32x4 macc[2] = {vzero, vzero};
  f32x4 pacc[2] = {vzero, vzero};
  f32x4 xacc    = vzero;

  __syncthreads();

#pragma unroll
  for (int st = 0; st < 4; ++st) {
    const int cur = st & 1;

    int4 qn;
    if (st < 3)  // depth-1 prefetch into registers
      qn = *reinterpret_cast<const int4*>(gq + (size_t)(st + 1) * 64 * NPACK);

#pragma unroll
    for (int t2 = 0; t2 < 2; ++t2) {
      const int kk = st * 2 + t2;
#pragma unroll
      for (int c = 0; c < 2; ++c) {
        const int* cp = &qt[cur][wloc + 2 * c][t2 * 32 + kg * 8];
        int4 qa = *reinterpret_cast<const int4*>(cp);      // ds_read_b128
        int4 qb = *reinterpret_cast<const int4*>(cp + 4);  // ds_read_b128
        union { bf16x8 v; unsigned short u[8]; } b;
        b.u[0] = (unsigned short)(0x4300 | ((qa.x >> sh) & 15));
        b.u[1] = (unsigned short)(0x4300 | ((qa.y >> sh) & 15));
        b.u[2] = (unsigned short)(0x4300 | ((qa.z >> sh) & 15));
        b.u[3] = (unsigned short)(0x4300 | ((qa.w >> sh) & 15));
        b.u[4] = (unsigned short)(0x4300 | ((qb.x >> sh) & 15));
        b.u[5] = (unsigned short)(0x4300 | ((qb.y >> sh) & 15));
        b.u[6] = (unsigned short)(0x4300 | ((qb.z >> sh) & 15));
        b.u[7] = (unsigned short)(0x4300 | ((qb.w >> sh) & 15));
        pacc[c] = __builtin_amdgcn_mfma_f32_16x16x32_bf16(a[kk], b.v, pacc[c], 0, 0, 0);
      }
      xacc = __builtin_amdgcn_mfma_f32_16x16x32_bf16(a[kk], ones.v, xacc, 0, 0, 0);

      if ((kk & 3) == 3) {  // group fold: macc += s * (P' - (z+128)*X)
        const int g = kk >> 2;
#pragma unroll
        for (int c = 0; c < 2; ++c)
#pragma unroll
          for (int r = 0; r < 4; ++r) {
            float t = fmaf(zn[g][c], xacc[r], pacc[c][r]);
            macc[c][r] = fmaf(s[g][c], t, macc[c][r]);
          }
        pacc[0] = vzero; pacc[1] = vzero; xacc = vzero;
      }
    }

    if (st < 3) {  // write prefetched tile (readers separated by prev barrier)
      qt[cur ^ 1][sw4 + 0][srow] = qn.x;
      qt[cur ^ 1][sw4 + 1][srow] = qn.y;
      qt[cur ^ 1][sw4 + 2][srow] = qn.z;
      qt[cur ^ 1][sw4 + 3][srow] = qn.w;
    }
    __syncthreads();
  }

  // epilogue: D col = lane&15, row = (lane>>4)*4 + r (m89-verified)
  float* pb = part + (size_t)ks * (M_DIM * N_DIM);
#pragma unroll
  for (int c = 0; c < 2; ++c) {
    int n = n0 + wv * 32 + c * 16 + c15;
#pragma unroll
    for (int r = 0; r < 4; ++r)
      pb[(kg * 4 + r) * N_DIM + n] = macc[c][r];
  }
}

// Generic fallback (round-3-proven verbatim), used only if ws is small.
__global__ __launch_bounds__(256) void gemm_awq_generic(
    const int* __restrict__ qw, const int* __restrict__ qz,
    const float* __restrict__ scales, const float* __restrict__ x,
    float* __restrict__ part, int nstep) {
  __shared__ int qt[16][36];
  int cb = blockIdx.x, ks = blockIdx.y;
  int n0 = cb * 128, w0 = cb * 16, k0 = ks * nstep * 32;
  int tid = threadIdx.x, lane = tid & 63, wv = tid >> 6;
  int c15 = lane & 15, kg = lane >> 4;
  int j = c15 & 7;
  int sh = ((j & 1) << 4) | ((j >> 1) << 2);
  int wloc = wv * 4 + (c15 >> 3);
  int srow = tid >> 3, swd = (tid & 7) * 2;
  const int* gq = qw + (size_t)(k0 + srow) * NPACK + w0 + swd;
  f32x4 acc[2] = {{0,0,0,0},{0,0,0,0}};
  int ngroups = nstep >> 2;
  for (int g = 0; g < ngroups; ++g) {
    int gid = (k0 >> 7) + g;
    float s[2], z[2];
#pragma unroll
    for (int c = 0; c < 2; ++c) {
      int n = n0 + wv * 32 + c * 16 + c15;
      float sv = scales[gid * N_DIM + n];
      int zw = qz[gid * NPACK + w0 + wloc + 2 * c];
      s[c] = sv; z[c] = -sv * (float)((zw >> sh) & 15);
    }
#pragma unroll
    for (int t4 = 0; t4 < 4; ++t4) {
      int kk = g * 4 + t4;
      int2 q2 = *reinterpret_cast<const int2*>(gq + (size_t)kk * 32 * NPACK);
      __syncthreads();
      qt[swd + 0][srow] = q2.x;
      qt[swd + 1][srow] = q2.y;
      __syncthreads();
      const float* xp = x + c15 * K_DIM + k0 + kk * 32 + kg * 8;
      float4 x0 = *reinterpret_cast<const float4*>(xp);
      float4 x1 = *reinterpret_cast<const float4*>(xp + 4);
      union { bf16x8 v; unsigned short u[8]; } a;
      a.u[0]=f2bf(x0.x); a.u[1]=f2bf(x0.y); a.u[2]=f2bf(x0.z); a.u[3]=f2bf(x0.w);
      a.u[4]=f2bf(x1.x); a.u[5]=f2bf(x1.y); a.u[6]=f2bf(x1.z); a.u[7]=f2bf(x1.w);
#pragma unroll
      for (int c = 0; c < 2; ++c) {
        const int* cp = &qt[wloc + 2 * c][kg * 8];
        int4 qa = *reinterpret_cast<const int4*>(cp);
        int4 qb = *reinterpret_cast<const int4*>(cp + 4);
        union { bf16x8 v; unsigned short u[8]; } b;
        float sv = s[c], zv = z[c];
        b.u[0] = f2bf(fmaf((float)((qa.x >> sh) & 15), sv, zv));
        b.u[1] = f2bf(fmaf((float)((qa.y >> sh) & 15), sv, zv));
        b.u[2] = f2bf(fmaf((float)((qa.z >> sh) & 15), sv, zv));
        b.u[3] = f2bf(fmaf((float)((qa.w >> sh) & 15), sv, zv));
        b.u[4] = f2bf(fmaf((float)((qb.x >> sh) & 15), sv, zv));
        b.u[5] = f2bf(fmaf((float)((qb.y >> sh) & 15), sv, zv));
        b.u[6] = f2bf(fmaf((float)((qb.z >> sh) & 15), sv, zv));
        b.u[7] = f2bf(fmaf((float)((qb.w >> sh) & 15), sv, zv));
        acc[c] = __builtin_amdgcn_mfma_f32_16x16x32_bf16(a.v, b.v, acc[c], 0, 0, 0);
      }
    }
  }
  float* pb = part + (size_t)ks * (M_DIM * N_DIM);
#pragma unroll
  for (int c = 0; c < 2; ++c) {
    int n = n0 + wv * 32 + c * 16 + c15;
#pragma unroll
    for (int r = 0; r < 4; ++r)
      pb[(kg * 4 + r) * N_DIM + n] = acc[c][r];
  }
}

// verbatim round-2-proven reduce
__global__ __launch_bounds__(256) void reduce_bias(
    const float* __restrict__ part, const float* __restrict__ bias,
    float* __restrict__ out, int split) {
  int i = blockIdx.x * 256 + threadIdx.x;
  if (i >= (M_DIM * N_DIM) / 4) return;
  int n = (i << 2) % N_DIM;
  float4 a = *reinterpret_cast<const float4*>(bias + n);
  for (int s = 0; s < split; ++s) {
    float4 p = reinterpret_cast<const float4*>(part)[(size_t)s * (M_DIM * N_DIM / 4) + i];
    a.x += p.x; a.y += p.y; a.z += p.z; a.w += p.w;
  }
  reinterpret_cast<float4*>(out)[i] = a;
}

extern "C" void kernel_launch(void* const* d_in, const int* in_sizes, int n_in,
                              void* d_out, int out_size, void* d_ws, size_t ws_size,
                              hipStream_t stream) {
  const float* x      = (const float*)d_in[0];
  const int*   qwp    = (const int*)d_in[1];
  const int*   qzp    = (const int*)d_in[2];
  const float* scales = (const float*)d_in[3];
  const float* bias   = (const float*)d_in[4];
  float* out = (float*)d_out;

  const size_t PART_ELEMS = (size_t)M_DIM * N_DIM;        // 176128
  const size_t PART16_BYTES = 16 * PART_ELEMS * 4;        // 11,272,192
  const size_t XB_BYTES = (size_t)M_DIM * K_DIM * 2;      // 131072

  if (ws_size >= PART16_BYTES + XB_BYTES) {
    // fast path: split=16, prep'd bf16 x
    float* part = (float*)d_ws;
    unsigned short* xb = (unsigned short*)((char*)d_ws + PART16_BYTES);
    prep_x<<<64, 256, 0, stream>>>(x, xb);
    gemm_awq_fast<<<dim3(NCB256, 16), 512, 0, stream>>>(qwp, qzp, scales, xb, part);
    reduce_bias<<<(M_DIM * N_DIM / 4 + 255) / 256, 256, 0, stream>>>(part, bias, out, 16);
  } else {
    int split = 16;
    while (split > 1 && (size_t)split * PART_ELEMS * 4 > ws_size) split >>= 1;
    float* part = (float*)d_ws;
    if ((size_t)split * PART_ELEMS * 4 > ws_size) {
      split = 1;
      part = out;   // reduce_bias adds bias in place (proven)
    }
    int nstep = 128 / split;
    gemm_awq_generic<<<dim3(NCB128, split), 256, 0, stream>>>(qwp, qzp, scales, x, part, nstep);
    reduce_bias<<<(M_DIM * N_DIM / 4 + 255) / 256, 256, 0, stream>>>(part, bias, out, split);
  }
}